// Round 1
// baseline (397.700 us; speedup 1.0000x reference)
//
#include <hip/hip_runtime.h>
#include <math.h>

#define B_SZ 24
#define D_EMBD 512
#define N_CLS 10000
#define CC 256
#define HH 196

#define S_SCALE 64.0f
#define COS_M 0.9004471023526769f
#define SIN_M 0.43496553411123023f
#define TH_C (-0.9004471023526769f)
#define MM_C 0.19573449035005357f
#define EPS_OT 0.1f
#define LOG_MU (-5.545177444479562f)   /* = log(1/256), also log_nu */
#define LM2 (-11.090354888959125f)     /* log_mu + log_nu */

// ---------------- K1a: normalize embeddings (24x512) ----------------
__global__ void k_embnorm(const float* __restrict__ emb, float* __restrict__ embn) {
    __shared__ float inv_s[B_SZ];
    int t = threadIdx.x, l = t & 63, w = t >> 6;
    for (int r = w; r < B_SZ; r += 4) {
        float s = 0.f;
        #pragma unroll
        for (int u = 0; u < 8; ++u) { float v = emb[r*D_EMBD + u*64 + l]; s = fmaf(v, v, s); }
        #pragma unroll
        for (int o = 1; o < 64; o <<= 1) s += __shfl_xor(s, o, 64);
        if (l == 0) inv_s[r] = rsqrtf(s);
    }
    __syncthreads();
    const float4* e4 = (const float4*)emb;
    float4* n4 = (float4*)embn;
    for (int i = t; i < (B_SZ*D_EMBD)/4; i += 256) {
        int r = i >> 7;                 // 128 float4 per row
        float4 v = e4[i]; float inv = inv_s[r];
        v.x *= inv; v.y *= inv; v.z *= inv; v.w *= inv;
        n4[i] = v;
    }
}

// ---------------- K1b: per-point squared norms (24x256) ----------------
__global__ void k_pnorm(const float* __restrict__ conv, float* __restrict__ pn) {
    int im = blockIdx.x, t = threadIdx.x, l = t & 63, w = t >> 6;
    const float* x = conv + im*CC*HH;
    for (int pt = w*64; pt < (w+1)*64; ++pt) {
        const float* xp = x + pt*HH;
        float s = 0.f;
        #pragma unroll
        for (int u = 0; u < 3; ++u) { float v = xp[u*64 + l]; s = fmaf(v, v, s); }
        if (l < 4) { float v = xp[192 + l]; s = fmaf(v, v, s); }
        #pragma unroll
        for (int o = 1; o < 64; o <<= 1) s += __shfl_xor(s, o, 64);
        if (l == 0) pn[im*CC + pt] = s;
    }
}

// ---------------- K1c: emb gram 24x24 (one wave per pair) + Dmat diag=0 ----------------
__global__ void k_dists(const float* __restrict__ embn, float* __restrict__ dists,
                        float* __restrict__ Dmat) {
    int t = threadIdx.x, l = t & 63, w = t >> 6;
    if (blockIdx.x == 0 && t < B_SZ) Dmat[t*B_SZ + t] = 0.f;
    int pid = blockIdx.x*4 + w;
    if (pid >= B_SZ*B_SZ) return;
    int i = pid / B_SZ, j = pid % B_SZ;
    float s = 0.f;
    #pragma unroll
    for (int u = 0; u < 8; ++u)
        s = fmaf(embn[i*D_EMBD + u*64 + l], embn[j*D_EMBD + u*64 + l], s);
    #pragma unroll
    for (int o = 1; o < 64; o <<= 1) s += __shfl_xor(s, o, 64);
    if (l == 0) dists[pid] = s;
}

// ---------------- K2: fused column-norm + GEMM + margin ----------------
// grid 625 blocks x 256 thr, 16 cols/block, 16 threads (k-chunks) per col.
__global__ __launch_bounds__(256) void k_arcface(const float* __restrict__ embn,
        const float* __restrict__ kern, const int* __restrict__ label,
        float* __restrict__ out) {
    __shared__ __align__(16) float es[B_SZ*D_EMBD];   // 48 KB; overlaid below
    __shared__ int lab_s[B_SZ];
    float* part = es;           // 16*400 floats, alias after sync
    float* resb = es + 6400;    // 400 floats

    int t = threadIdx.x;
    {
        const float4* s4 = (const float4*)embn;
        float4* d4 = (float4*)es;
        for (int i = t; i < (B_SZ*D_EMBD)/4; i += 256) d4[i] = s4[i];
    }
    if (t < B_SZ) lab_s[t] = label[t];
    __syncthreads();

    int cc = t & 15, kc = t >> 4;
    int c = blockIdx.x*16 + cc;
    float acc[B_SZ];
    #pragma unroll
    for (int r = 0; r < B_SZ; ++r) acc[r] = 0.f;
    float cn = 0.f;
    int k0 = kc*32;
    for (int u = 0; u < 8; ++u) {
        int kb = k0 + u*4;
        float kv0 = kern[(kb+0)*N_CLS + c];
        float kv1 = kern[(kb+1)*N_CLS + c];
        float kv2 = kern[(kb+2)*N_CLS + c];
        float kv3 = kern[(kb+3)*N_CLS + c];
        cn = fmaf(kv0,kv0,cn); cn = fmaf(kv1,kv1,cn);
        cn = fmaf(kv2,kv2,cn); cn = fmaf(kv3,kv3,cn);
        #pragma unroll
        for (int r = 0; r < B_SZ; ++r) {
            const float4 e = *(const float4*)&es[r*D_EMBD + kb];
            acc[r] = fmaf(e.x, kv0, acc[r]);
            acc[r] = fmaf(e.y, kv1, acc[r]);
            acc[r] = fmaf(e.z, kv2, acc[r]);
            acc[r] = fmaf(e.w, kv3, acc[r]);
        }
    }
    __syncthreads();   // es reads done everywhere before aliased writes
    #pragma unroll
    for (int r = 0; r < B_SZ; ++r) part[kc*400 + cc*25 + r] = acc[r];
    part[kc*400 + cc*25 + 24] = cn;
    __syncthreads();
    for (int j = t; j < 400; j += 256) {
        float s = 0.f;
        #pragma unroll
        for (int kk = 0; kk < 16; ++kk) s += part[kk*400 + j];
        resb[j] = s;
    }
    __syncthreads();
    for (int o = t; o < 384; o += 256) {
        int r = o >> 4, c2 = o & 15;
        int col = blockIdx.x*16 + c2;
        float dot = resb[c2*25 + r];
        float inv = rsqrtf(resb[c2*25 + 24]);
        float cosv = fminf(fmaxf(dot*inv, -1.f), 1.f);
        float oc = cosv * S_SCALE;
        float af = oc;
        if (lab_s[r] == col) {
            float tl = cosv;
            float sint = sqrtf(fmaxf(1.f - tl*tl, 0.f));
            float ctm = tl*COS_M - sint*SIN_M;
            float ftl = (tl > TH_C) ? ctm : (tl - MM_C);
            af = ftl * S_SCALE;
        }
        out[r*N_CLS + col] = af;            // arcfaceloss
        out[240001 + r*N_CLS + col] = oc;   // origin_cos * S
    }
}

// ---------------- K3: per-pair cdist GEMM + log-domain Sinkhorn ----------------
// 276 blocks (a<b) x 1024 threads. Thread owns an 8x8 register tile of C.
__global__ __launch_bounds__(1024) void k_pairs(const float* __restrict__ conv,
        const float* __restrict__ pnorm, float* __restrict__ Dmat) {
    __shared__ __align__(16) float As[7168];     // 28 x 256 (k-major), 28 KB
    __shared__ __align__(16) float Bs[7168];     // 28 KB
    __shared__ float na_s[CC], nb_s[CC], gvs[CC], cm10[CC];
    __shared__ float wred[16];
    __shared__ float scal[2];                    // [0]=gmax10 [1]=fmax10
    float* red = As;                             // 16x256 scratch, alias after GEMM

    int t = threadIdx.x;
    int tr = t >> 5, tc = t & 31;
    int w = t >> 6;

    // pair index -> (a, b), a < b
    int rem = blockIdx.x, a = 0;
    while (rem >= 23 - a) { rem -= 23 - a; ++a; }
    int b = a + 1 + rem;

    const float* xa = conv + a*CC*HH;
    const float* xb = conv + b*CC*HH;
    if (t < CC) { na_s[t] = pnorm[a*CC + t]; nb_s[t] = pnorm[b*CC + t]; }

    float acc[8][8];
    #pragma unroll
    for (int r = 0; r < 8; ++r)
        #pragma unroll
        for (int c = 0; c < 8; ++c) acc[r][c] = 0.f;

    // GEMM: G = xa . xb^T over k=196, LDS tiles of 28 (7 float4 per row-chunk)
    for (int ks = 0; ks < HH; ks += 28) {
        __syncthreads();
        for (int v = t; v < 1792; v += 1024) {
            int i = v / 7, pos = v - (v/7)*7;
            float4 va = ((const float4*)(xa + i*HH + ks))[pos];
            float4 vb = ((const float4*)(xb + i*HH + ks))[pos];
            int sb = pos*4;
            As[(sb+0)*CC + i] = va.x; As[(sb+1)*CC + i] = va.y;
            As[(sb+2)*CC + i] = va.z; As[(sb+3)*CC + i] = va.w;
            Bs[(sb+0)*CC + i] = vb.x; Bs[(sb+1)*CC + i] = vb.y;
            Bs[(sb+2)*CC + i] = vb.z; Bs[(sb+3)*CC + i] = vb.w;
        }
        __syncthreads();
        for (int k = 0; k < 28; ++k) {
            const float4* ap = (const float4*)&As[k*CC + tr*8];
            const float4* bp = (const float4*)&Bs[k*CC + tc*8];
            float4 a0 = ap[0], a1 = ap[1];
            float4 b0 = bp[0], b1 = bp[1];
            float av[8] = {a0.x,a0.y,a0.z,a0.w,a1.x,a1.y,a1.z,a1.w};
            float bv[8] = {b0.x,b0.y,b0.z,b0.w,b1.x,b1.y,b1.z,b1.w};
            #pragma unroll
            for (int r = 0; r < 8; ++r)
                #pragma unroll
                for (int c = 0; c < 8; ++c)
                    acc[r][c] = fmaf(av[r], bv[c], acc[r][c]);
        }
    }
    __syncthreads();

    // C = sqrt(max(na+nb-2G,0)+1e-12), in registers
    float C[8][8];
    #pragma unroll
    for (int r = 0; r < 8; ++r) {
        float n2a = na_s[tr*8 + r];
        #pragma unroll
        for (int c = 0; c < 8; ++c) {
            float d2 = fmaxf(n2a + nb_s[tc*8 + c] - 2.f*acc[r][c], 0.f);
            C[r][c] = sqrtf(d2 + 1e-12f);
        }
    }
    // row mins (x10) -> regs; lanes sharing tr are a contiguous 32-lane half
    float rm10[8];
    #pragma unroll
    for (int r = 0; r < 8; ++r) {
        float m = C[r][0];
        #pragma unroll
        for (int c = 1; c < 8; ++c) m = fminf(m, C[r][c]);
        #pragma unroll
        for (int o = 1; o < 32; o <<= 1) m = fminf(m, __shfl_xor(m, o, 64));
        rm10[r] = 10.f * m;
    }
    // col mins (x10) -> LDS (cross-wave via red)
    {
        float cml[8];
        #pragma unroll
        for (int c = 0; c < 8; ++c) {
            float m = C[0][c];
            #pragma unroll
            for (int r = 1; r < 8; ++r) m = fminf(m, C[r][c]);
            m = fminf(m, __shfl_xor(m, 32, 64));
            cml[c] = m;
        }
        if ((t & 32) == 0) {
            #pragma unroll
            for (int c = 0; c < 8; ++c) red[w*CC + tc*8 + c] = cml[c];
        }
    }
    __syncthreads();
    if (t < CC) {
        float m = red[t];
        #pragma unroll
        for (int ww = 1; ww < 16; ++ww) m = fminf(m, red[ww*CC + t]);
        cm10[t] = 10.f * m;
        gvs[t] = 0.f;
    }
    if (t == 0) scal[0] = 0.f;
    __syncthreads();

    // 6 Sinkhorn iterations; f kept in registers (replicated over the 32 lanes/tr)
    float f8[8];
    for (int it = 0; it < 6; ++it) {
        float g10[8];
        #pragma unroll
        for (int c = 0; c < 8; ++c) g10[c] = 10.f * gvs[tc*8 + c];
        float gmax10 = scal[0];
        #pragma unroll
        for (int r = 0; r < 8; ++r) {
            float off = rm10[r] - gmax10;           // = -shift (safe LSE shift)
            float s = 0.f;
            #pragma unroll
            for (int c = 0; c < 8; ++c)
                s += __expf(fmaf(-10.f, C[r][c], g10[c] + off));
            #pragma unroll
            for (int o = 1; o < 32; o <<= 1) s += __shfl_xor(s, o, 64);
            f8[r] = -EPS_OT * ((gmax10 - rm10[r]) + __logf(s) + LOG_MU);
        }
        // fmax across 256 rows
        float fm = f8[0];
        #pragma unroll
        for (int r = 1; r < 8; ++r) fm = fmaxf(fm, f8[r]);
        #pragma unroll
        for (int o = 1; o < 64; o <<= 1) fm = fmaxf(fm, __shfl_xor(fm, o, 64));
        if ((t & 63) == 0) wred[w] = fm;
        __syncthreads();
        if (t == 0) {
            float m = wred[0];
            #pragma unroll
            for (int ww = 1; ww < 16; ++ww) m = fmaxf(m, wred[ww]);
            scal[1] = 10.f * m;
        }
        __syncthreads();
        float fmax10 = scal[1];
        // g update: partial column sums over this thread's 8 rows
        float prt[8];
        #pragma unroll
        for (int c = 0; c < 8; ++c) {
            float offc = cm10[tc*8 + c] - fmax10;
            float s = 0.f;
            #pragma unroll
            for (int r = 0; r < 8; ++r)
                s += __expf(fmaf(-10.f, C[r][c], fmaf(10.f, f8[r], offc)));
            s += __shfl_xor(s, 32, 64);
            prt[c] = s;
        }
        if ((t & 32) == 0) {
            #pragma unroll
            for (int c = 0; c < 8; ++c) red[w*CC + tc*8 + c] = prt[c];
        }
        __syncthreads();
        if (t < CC) {
            float ssum = red[t];
            #pragma unroll
            for (int ww = 1; ww < 16; ++ww) ssum += red[ww*CC + t];
            float gj = -EPS_OT * ((fmax10 - cm10[t]) + __logf(ssum) + LOG_MU);
            gvs[t] = gj;
            float gm = gj;
            #pragma unroll
            for (int o = 1; o < 64; o <<= 1) gm = fmaxf(gm, __shfl_xor(gm, o, 64));
            if ((t & 63) == 0) wred[t >> 6] = gm;
        }
        __syncthreads();
        if (t == 0)
            scal[0] = 10.f * fmaxf(fmaxf(wred[0], wred[1]), fmaxf(wred[2], wred[3]));
        __syncthreads();
    }

    // D = sum(T * C), T = exp(10(f+g-C) + log_mu + log_nu)
    float g8[8];
    #pragma unroll
    for (int c = 0; c < 8; ++c) g8[c] = gvs[tc*8 + c];
    float dsum = 0.f;
    #pragma unroll
    for (int r = 0; r < 8; ++r) {
        float fr10 = 10.f * f8[r];
        #pragma unroll
        for (int c = 0; c < 8; ++c) {
            float Cc = C[r][c];
            float arg = fmaf(-10.f, Cc, fr10 + fmaf(10.f, g8[c], LM2));
            dsum = fmaf(__expf(arg), Cc, dsum);
        }
    }
    #pragma unroll
    for (int o = 1; o < 64; o <<= 1) dsum += __shfl_xor(dsum, o, 64);
    if ((t & 63) == 0) wred[w] = dsum;
    __syncthreads();
    if (t == 0) {
        float s = 0.f;
        #pragma unroll
        for (int ww = 0; ww < 16; ++ww) s += wred[ww];
        Dmat[a*B_SZ + b] = s;
        Dmat[b*B_SZ + a] = s;
    }
}

// ---------------- K4: triplet scan + scalar outputs ----------------
__global__ void k_final(const float* __restrict__ dists, const float* __restrict__ Dmat,
                        const int* __restrict__ label, float* __restrict__ out) {
    __shared__ float ds[576], Dm[576];
    __shared__ int lab[B_SZ];
    __shared__ float wls[4]; __shared__ int wnp[4], wot[4];
    int t = threadIdx.x;
    for (int i = t; i < 576; i += 256) { ds[i] = dists[i]; Dm[i] = Dmat[i]; }
    if (t < B_SZ) lab[t] = label[t];
    __syncthreads();
    int np = 0, ot = 0; float wsum = 0.f;
    for (int idx = t; idx < 24*24*24; idx += 256) {
        int a2 = idx / 576;
        int rest = idx - a2*576;
        int p2 = rest / 24;
        int n2 = rest - p2*24;
        int la = lab[a2];
        if (la == lab[p2] && la != lab[n2]) {
            float diff = ds[a2*24 + n2] - ds[a2*24 + p2];   // cos(a,n)-cos(a,p) > 0
            if (diff > 0.f) {
                ++np;
                float dd = Dm[a2*24 + p2] - Dm[a2*24 + n2];
                if (dd > 0.f) { ++ot; wsum += dd; }
            }
        }
    }
    #pragma unroll
    for (int o = 1; o < 64; o <<= 1) {
        np += __shfl_xor(np, o, 64);
        ot += __shfl_xor(ot, o, 64);
        wsum += __shfl_xor(wsum, o, 64);
    }
    int w = t >> 6;
    if ((t & 63) == 0) { wnp[w] = np; wot[w] = ot; wls[w] = wsum; }
    __syncthreads();
    if (t == 0) {
        int tnp = wnp[0]+wnp[1]+wnp[2]+wnp[3];
        int tot = wot[0]+wot[1]+wot[2]+wot[3];
        float tws = wls[0]+wls[1]+wls[2]+wls[3];
        int den = tot > 1 ? tot : 1;
        float wl = (tws > 0.f) ? tws / (float)den : 0.f;
        out[240000] = wl;            // wass_loss
        out[480001] = (float)tnp;    // n_cosine_pair
        out[480002] = (float)tot;    // ot_pair
    }
}

extern "C" void kernel_launch(void* const* d_in, const int* in_sizes, int n_in,
                              void* d_out, int out_size, void* d_ws, size_t ws_size,
                              hipStream_t stream) {
    (void)in_sizes; (void)n_in; (void)out_size; (void)ws_size;
    const float* emb  = (const float*)d_in[0];
    const float* conv = (const float*)d_in[1];
    const float* kern = (const float*)d_in[2];
    const int*   lab  = (const int*)d_in[3];
    float* out = (float*)d_out;
    float* ws  = (float*)d_ws;
    float* embn  = ws;            // 12288 floats
    float* pnorm = ws + 12288;    // 6144
    float* dists = ws + 18432;    // 576
    float* Dmat  = ws + 19008;    // 576

    k_embnorm<<<1, 256, 0, stream>>>(emb, embn);
    k_pnorm<<<24, 256, 0, stream>>>(conv, pnorm);
    k_dists<<<144, 256, 0, stream>>>(embn, dists, Dmat);
    k_arcface<<<625, 256, 0, stream>>>(embn, kern, lab, out);
    k_pairs<<<276, 1024, 0, stream>>>(conv, pnorm, Dmat);
    k_final<<<1, 256, 0, stream>>>(dists, Dmat, lab, out);
}

// Round 2
// 283.149 us; speedup vs baseline: 1.4046x; 1.4046x over previous
//
#include <hip/hip_runtime.h>
#include <math.h>

#define B_SZ 24
#define D_EMBD 512
#define N_CLS 10000
#define CC 256
#define HH 196

#define S_SCALE 64.0f
#define COS_M 0.9004471023526769f
#define SIN_M 0.43496553411123023f
#define TH_C (-0.9004471023526769f)
#define MM_C 0.19573449035005357f
#define EPS_OT 0.1f
#define LOG_MU (-5.545177444479562f)
#define LM2 (-11.090354888959125f)
// base-2 scaled Sinkhorn units: Ceps2 = C * log2(e)/eps
#define KSC 14.4269504088896f          /* 10*log2(e) */
#define C2E 0.0693147180559945f        /* 1/KSC = eps*ln2 */

typedef short bfrag8 __attribute__((ext_vector_type(8)));
typedef float facc4 __attribute__((ext_vector_type(4)));

#if __has_builtin(__builtin_amdgcn_exp2f)
#define EXP2F(x) __builtin_amdgcn_exp2f(x)
#else
#define EXP2F(x) exp2f(x)
#endif
#if __has_builtin(__builtin_amdgcn_logf)
#define LOG2F(x) __builtin_amdgcn_logf(x)
#else
#define LOG2F(x) __log2f(x)
#endif

__device__ inline unsigned short f2bf_rne(float x) {
    union { float f; unsigned u; } cv; cv.f = x;
    unsigned r = cv.u + 0x7FFFu + ((cv.u >> 16) & 1u);
    return (unsigned short)(r >> 16);
}
__device__ inline float bf2f(unsigned short h) {
    union { unsigned u; float f; } cv; cv.u = ((unsigned)h) << 16; return cv.f;
}

// ---------------- K1a: normalize embeddings (24x512) ----------------
__global__ void k_embnorm(const float* __restrict__ emb, float* __restrict__ embn) {
    __shared__ float inv_s[B_SZ];
    int t = threadIdx.x, l = t & 63, w = t >> 6;
    for (int r = w; r < B_SZ; r += 4) {
        float s = 0.f;
        #pragma unroll
        for (int u = 0; u < 8; ++u) { float v = emb[r*D_EMBD + u*64 + l]; s = fmaf(v, v, s); }
        #pragma unroll
        for (int o = 1; o < 64; o <<= 1) s += __shfl_xor(s, o, 64);
        if (l == 0) inv_s[r] = rsqrtf(s);
    }
    __syncthreads();
    const float4* e4 = (const float4*)emb;
    float4* n4 = (float4*)embn;
    for (int i = t; i < (B_SZ*D_EMBD)/4; i += 256) {
        int r = i >> 7;
        float4 v = e4[i]; float inv = inv_s[r];
        v.x *= inv; v.y *= inv; v.z *= inv; v.w *= inv;
        n4[i] = v;
    }
}

// ---------------- K1b: per-point squared norms (24x256) ----------------
__global__ void k_pnorm(const float* __restrict__ conv, float* __restrict__ pn) {
    int im = blockIdx.x, t = threadIdx.x, l = t & 63, w = t >> 6;
    const float* x = conv + im*CC*HH;
    for (int pt = w*64; pt < (w+1)*64; ++pt) {
        const float* xp = x + pt*HH;
        float s = 0.f;
        #pragma unroll
        for (int u = 0; u < 3; ++u) { float v = xp[u*64 + l]; s = fmaf(v, v, s); }
        if (l < 4) { float v = xp[192 + l]; s = fmaf(v, v, s); }
        #pragma unroll
        for (int o = 1; o < 64; o <<= 1) s += __shfl_xor(s, o, 64);
        if (l == 0) pn[im*CC + pt] = s;
    }
}

// ---------------- K1c: emb gram 24x24 + Dmat diag=0 ----------------
__global__ void k_dists(const float* __restrict__ embn, float* __restrict__ dists,
                        float* __restrict__ Dmat) {
    int t = threadIdx.x, l = t & 63, w = t >> 6;
    if (blockIdx.x == 0 && t < B_SZ) Dmat[t*B_SZ + t] = 0.f;
    int pid = blockIdx.x*4 + w;
    if (pid >= B_SZ*B_SZ) return;
    int i = pid / B_SZ, j = pid % B_SZ;
    float s = 0.f;
    #pragma unroll
    for (int u = 0; u < 8; ++u)
        s = fmaf(embn[i*D_EMBD + u*64 + l], embn[j*D_EMBD + u*64 + l], s);
    #pragma unroll
    for (int o = 1; o < 64; o <<= 1) s += __shfl_xor(s, o, 64);
    if (l == 0) dists[pid] = s;
}

// ---------------- K2: fused column-norm + GEMM + margin ----------------
__global__ __launch_bounds__(256) void k_arcface(const float* __restrict__ embn,
        const float* __restrict__ kern, const int* __restrict__ label,
        float* __restrict__ out) {
    __shared__ __align__(16) float es[B_SZ*D_EMBD];
    __shared__ int lab_s[B_SZ];
    float* part = es;
    float* resb = es + 6400;

    int t = threadIdx.x;
    {
        const float4* s4 = (const float4*)embn;
        float4* d4 = (float4*)es;
        for (int i = t; i < (B_SZ*D_EMBD)/4; i += 256) d4[i] = s4[i];
    }
    if (t < B_SZ) lab_s[t] = label[t];
    __syncthreads();

    int cc = t & 15, kc = t >> 4;
    int c = blockIdx.x*16 + cc;
    float acc[B_SZ];
    #pragma unroll
    for (int r = 0; r < B_SZ; ++r) acc[r] = 0.f;
    float cn = 0.f;
    int k0 = kc*32;
    for (int u = 0; u < 8; ++u) {
        int kb = k0 + u*4;
        float kv0 = kern[(kb+0)*N_CLS + c];
        float kv1 = kern[(kb+1)*N_CLS + c];
        float kv2 = kern[(kb+2)*N_CLS + c];
        float kv3 = kern[(kb+3)*N_CLS + c];
        cn = fmaf(kv0,kv0,cn); cn = fmaf(kv1,kv1,cn);
        cn = fmaf(kv2,kv2,cn); cn = fmaf(kv3,kv3,cn);
        #pragma unroll
        for (int r = 0; r < B_SZ; ++r) {
            const float4 e = *(const float4*)&es[r*D_EMBD + kb];
            acc[r] = fmaf(e.x, kv0, acc[r]);
            acc[r] = fmaf(e.y, kv1, acc[r]);
            acc[r] = fmaf(e.z, kv2, acc[r]);
            acc[r] = fmaf(e.w, kv3, acc[r]);
        }
    }
    __syncthreads();
    #pragma unroll
    for (int r = 0; r < B_SZ; ++r) part[kc*400 + cc*25 + r] = acc[r];
    part[kc*400 + cc*25 + 24] = cn;
    __syncthreads();
    for (int j = t; j < 400; j += 256) {
        float s = 0.f;
        #pragma unroll
        for (int kk = 0; kk < 16; ++kk) s += part[kk*400 + j];
        resb[j] = s;
    }
    __syncthreads();
    for (int o = t; o < 384; o += 256) {
        int r = o >> 4, c2 = o & 15;
        int col = blockIdx.x*16 + c2;
        float dot = resb[c2*25 + r];
        float inv = rsqrtf(resb[c2*25 + 24]);
        float cosv = fminf(fmaxf(dot*inv, -1.f), 1.f);
        float oc = cosv * S_SCALE;
        float af = oc;
        if (lab_s[r] == col) {
            float tl = cosv;
            float sint = sqrtf(fmaxf(1.f - tl*tl, 0.f));
            float ctm = tl*COS_M - sint*SIN_M;
            float ftl = (tl > TH_C) ? ctm : (tl - MM_C);
            af = ftl * S_SCALE;
        }
        out[r*N_CLS + col] = af;
        out[240001 + r*N_CLS + col] = oc;
    }
}

// ---------------- K3: split-bf16 MFMA GEMM + base-2 log-domain Sinkhorn ----------------
// 276 blocks (a<b) x 1024 threads (16 waves, 4x4 wave grid, 64x64 tile/wave).
__global__ __launch_bounds__(1024) void k_pairs(const float* __restrict__ conv,
        const float* __restrict__ pnorm, float* __restrict__ Dmat) {
    __shared__ __align__(16) char smem[65536];
    // GEMM phase overlay: 4 staging buffers [256 rows][32 k] bf16 (16 KB each)
    unsigned short* Ah = (unsigned short*)smem;
    unsigned short* Al = Ah + 8192;
    unsigned short* Bh = Al + 8192;
    unsigned short* Bl = Bh + 8192;
    // Sinkhorn phase overlay (all used strictly after GEMM's last barrier)
    float* rowred = (float*)smem;        // [4][256]
    float* colred = rowred + 1024;       // [4][256]
    float* rm_l   = colred + 1024;       // [256]
    float* cm_l   = rm_l + 256;
    float* f_l    = cm_l + 256;
    float* g_l    = f_l + 256;
    float* na_s   = g_l + 256;
    float* nb_s   = na_s + 256;
    float* wredF  = nb_s + 256;          // [4]
    float* wredG  = wredF + 4;           // [4]
    float* wredD  = wredG + 4;           // [16]

    const int t = threadIdx.x;
    const int w = t >> 6;
    const int wr = w >> 2, wc = w & 3;
    const int q = (t >> 4) & 3, c0 = t & 15;
    const int R0 = wr * 64, C0 = wc * 64;

    // pair index -> (a, b), a < b
    int rem = blockIdx.x, a = 0;
    while (rem >= 23 - a) { rem -= 23 - a; ++a; }
    int b = a + 1 + rem;
    const float* xa = conv + a*CC*HH;
    const float* xb = conv + b*CC*HH;

    const int sn = (t >> 2) & 255;       // staging row
    const int sch = t & 3;               // staging 8-k chunk

    facc4 acc[4][4];
    #pragma unroll
    for (int i = 0; i < 4; ++i)
        #pragma unroll
        for (int j = 0; j < 4; ++j) acc[i][j] = (facc4){0.f, 0.f, 0.f, 0.f};

    // ---- GEMM: G = Xa . Xb^T, K padded 196 -> 224, 7 K-steps of 32 ----
    for (int ks = 0; ks < 224; ks += 32) {
        __syncthreads();
        #pragma unroll
        for (int p = 0; p < 2; ++p) {
            int k0 = ks + sch*8;
            const float* src = (p ? xb : xa) + sn*HH + k0;
            float v[8];
            if (k0 + 8 <= HH) {
                const float4* s4 = (const float4*)src;
                float4 u0 = s4[0], u1 = s4[1];
                v[0]=u0.x; v[1]=u0.y; v[2]=u0.z; v[3]=u0.w;
                v[4]=u1.x; v[5]=u1.y; v[6]=u1.z; v[7]=u1.w;
            } else {
                #pragma unroll
                for (int j = 0; j < 8; ++j) v[j] = (k0 + j < HH) ? src[j] : 0.f;
            }
            union { unsigned short s[8]; bfrag8 v8; } uh, ul;
            #pragma unroll
            for (int j = 0; j < 8; ++j) {
                unsigned short hb = f2bf_rne(v[j]);
                uh.s[j] = hb;
                ul.s[j] = f2bf_rne(v[j] - bf2f(hb));
            }
            unsigned short* dh = (p ? Bh : Ah) + sn*32 + sch*8;
            unsigned short* dl = (p ? Bl : Al) + sn*32 + sch*8;
            *(bfrag8*)dh = uh.v8;
            *(bfrag8*)dl = ul.v8;
        }
        __syncthreads();
        bfrag8 bh4[4], bl4[4];
        #pragma unroll
        for (int tj = 0; tj < 4; ++tj) {
            int col = C0 + tj*16 + c0;
            bh4[tj] = *(const bfrag8*)(Bh + col*32 + q*8);
            bl4[tj] = *(const bfrag8*)(Bl + col*32 + q*8);
        }
        #pragma unroll
        for (int ti = 0; ti < 4; ++ti) {
            int row = R0 + ti*16 + c0;
            bfrag8 ah = *(const bfrag8*)(Ah + row*32 + q*8);
            bfrag8 al = *(const bfrag8*)(Al + row*32 + q*8);
            #pragma unroll
            for (int tj = 0; tj < 4; ++tj) {
                acc[ti][tj] = __builtin_amdgcn_mfma_f32_16x16x32_bf16(ah, bh4[tj], acc[ti][tj], 0, 0, 0);
                acc[ti][tj] = __builtin_amdgcn_mfma_f32_16x16x32_bf16(ah, bl4[tj], acc[ti][tj], 0, 0, 0);
                acc[ti][tj] = __builtin_amdgcn_mfma_f32_16x16x32_bf16(al, bh4[tj], acc[ti][tj], 0, 0, 0);
            }
        }
    }
    __syncthreads();   // GEMM frag reads done; LDS now reused for Sinkhorn

    if (t < 256) {
        na_s[t] = pnorm[a*CC + t];
        nb_s[t] = pnorm[b*CC + t];
        g_l[t] = 0.f;
    }
    if (t < 4) wredG[t] = 0.f;
    __syncthreads();

    // C/D layout (16x16x32): row = R0 + ti*16 + q*4 + reg, col = C0 + tj*16 + c0
    // Ceps2 = KSC * sqrt(max(na+nb-2G,0)+1e-12)
    facc4 Cv[4][4];
    float nbv[4];
    #pragma unroll
    for (int tj = 0; tj < 4; ++tj) nbv[tj] = nb_s[C0 + tj*16 + c0];
    #pragma unroll
    for (int ti = 0; ti < 4; ++ti) {
        facc4 nav = *(const facc4*)&na_s[R0 + ti*16 + q*4];
        #pragma unroll
        for (int tj = 0; tj < 4; ++tj) {
            facc4 cc;
            #pragma unroll
            for (int r = 0; r < 4; ++r) {
                float d2 = fmaxf(nav[r] + nbv[tj] - 2.f*acc[ti][tj][r], 0.f);
                cc[r] = KSC * sqrtf(d2 + 1e-12f);
            }
            Cv[ti][tj] = cc;
        }
    }

    // tournament target indices (fixed per lane)
    const int istar = ((c0&1)<<3) | ((c0&2)<<1) | ((c0&4)>>1) | ((c0&8)>>3);
    const int rowstar = R0 + (istar>>2)*16 + q*4 + (istar&3);
    const int tjstar = ((q&1)<<1) | (q>>1);
    const int colstar = C0 + tjstar*16 + c0;

    // ---- row/col mins of Ceps2 (for safe LSE shifts) ----
    {
        float v16[16];
        #pragma unroll
        for (int ti = 0; ti < 4; ++ti)
            #pragma unroll
            for (int r = 0; r < 4; ++r)
                v16[ti*4+r] = fminf(fminf(Cv[ti][0][r], Cv[ti][1][r]),
                                    fminf(Cv[ti][2][r], Cv[ti][3][r]));
        #pragma unroll
        for (int p = 0; p < 4; ++p) {
            const int m = 1 << p, hsz = 8 >> p;
            const bool hi = (c0 >> p) & 1;
            #pragma unroll
            for (int j = 0; j < hsz; ++j) {
                float mine = hi ? v16[j+hsz] : v16[j];
                float send = hi ? v16[j] : v16[j+hsz];
                v16[j] = fminf(mine, __shfl_xor(send, m, 64));
            }
        }
        rowred[wc*256 + rowstar] = v16[0];

        float w4[4];
        #pragma unroll
        for (int tj = 0; tj < 4; ++tj) {
            float m = Cv[0][tj][0];
            #pragma unroll
            for (int ti = 0; ti < 4; ++ti)
                #pragma unroll
                for (int r = 0; r < 4; ++r) m = fminf(m, Cv[ti][tj][r]);
            w4[tj] = m;
        }
        #pragma unroll
        for (int p = 0; p < 2; ++p) {
            const int m = 16 << p, hsz = 2 >> p;
            const bool hi = (q >> p) & 1;
            #pragma unroll
            for (int j = 0; j < hsz; ++j) {
                float mine = hi ? w4[j+hsz] : w4[j];
                float send = hi ? w4[j] : w4[j+hsz];
                w4[j] = fminf(mine, __shfl_xor(send, m, 64));
            }
        }
        colred[wr*256 + colstar] = w4[0];
    }
    __syncthreads();
    if (t < 256) {
        rm_l[t] = fminf(fminf(rowred[t], rowred[256+t]), fminf(rowred[512+t], rowred[768+t]));
        cm_l[t] = fminf(fminf(colred[t], colred[256+t]), fminf(colred[512+t], colred[768+t]));
    }
    __syncthreads();

    // ---- 6 Sinkhorn iterations, base-2 scaled duals F,G ----
    #pragma unroll 1
    for (int it = 0; it < 6; ++it) {
        // row update: F_r = 8 + rm_r - Gmax - log2(sum_c 2^{(G_c + rm_r - Gmax) - Ceps2})
        float Gmax = fmaxf(fmaxf(wredG[0], wredG[1]), fmaxf(wredG[2], wredG[3]));
        float G4[4];
        #pragma unroll
        for (int tj = 0; tj < 4; ++tj) G4[tj] = g_l[C0 + tj*16 + c0];
        float v16[16];
        #pragma unroll
        for (int ti = 0; ti < 4; ++ti) {
            facc4 rmv = *(const facc4*)&rm_l[R0 + ti*16 + q*4];
            #pragma unroll
            for (int r = 0; r < 4; ++r) {
                float off = rmv[r] - Gmax;
                float s = 0.f;
                #pragma unroll
                for (int tj = 0; tj < 4; ++tj)
                    s += EXP2F(G4[tj] + off - Cv[ti][tj][r]);
                v16[ti*4+r] = s;
            }
        }
        #pragma unroll
        for (int p = 0; p < 4; ++p) {
            const int m = 1 << p, hsz = 8 >> p;
            const bool hi = (c0 >> p) & 1;
            #pragma unroll
            for (int j = 0; j < hsz; ++j) {
                float mine = hi ? v16[j+hsz] : v16[j];
                float send = hi ? v16[j] : v16[j+hsz];
                v16[j] = mine + __shfl_xor(send, m, 64);
            }
        }
        rowred[wc*256 + rowstar] = v16[0];
        __syncthreads();
        if (t < 256) {
            float s = rowred[t] + rowred[256+t] + rowred[512+t] + rowred[768+t];
            float F = 8.f + rm_l[t] - Gmax - LOG2F(s);
            f_l[t] = F;
            float m = F;
            #pragma unroll
            for (int o = 1; o < 64; o <<= 1) m = fmaxf(m, __shfl_xor(m, o, 64));
            if ((t & 63) == 0) wredF[t >> 6] = m;
        }
        __syncthreads();

        // col update: G_c = 8 + cm_c - Fmax - log2(sum_r 2^{(F_r + cm_c - Fmax) - Ceps2})
        float Fmax = fmaxf(fmaxf(wredF[0], wredF[1]), fmaxf(wredF[2], wredF[3]));
        facc4 Ff[4];
        #pragma unroll
        for (int ti = 0; ti < 4; ++ti) Ff[ti] = *(const facc4*)&f_l[R0 + ti*16 + q*4];
        float w4[4];
        #pragma unroll
        for (int tj = 0; tj < 4; ++tj) {
            float offc = cm_l[C0 + tj*16 + c0] - Fmax;
            float s = 0.f;
            #pragma unroll
            for (int ti = 0; ti < 4; ++ti)
                #pragma unroll
                for (int r = 0; r < 4; ++r)
                    s += EXP2F(Ff[ti][r] + offc - Cv[ti][tj][r]);
            w4[tj] = s;
        }
        #pragma unroll
        for (int p = 0; p < 2; ++p) {
            const int m = 16 << p, hsz = 2 >> p;
            const bool hi = (q >> p) & 1;
            #pragma unroll
            for (int j = 0; j < hsz; ++j) {
                float mine = hi ? w4[j+hsz] : w4[j];
                float send = hi ? w4[j] : w4[j+hsz];
                w4[j] = mine + __shfl_xor(send, m, 64);
            }
        }
        colred[wr*256 + colstar] = w4[0];
        __syncthreads();
        if (t < 256) {
            float s = colred[t] + colred[256+t] + colred[512+t] + colred[768+t];
            float G = 8.f + cm_l[t] - Fmax - LOG2F(s);
            g_l[t] = G;
            float m = G;
            #pragma unroll
            for (int o = 1; o < 64; o <<= 1) m = fmaxf(m, __shfl_xor(m, o, 64));
            if ((t & 63) == 0) wredG[t >> 6] = m;
        }
        __syncthreads();
    }

    // ---- D = sum(T*C), T = 2^{F + G - Ceps2 - 16}, C = Ceps2 * C2E ----
    {
        facc4 Ff[4];
        #pragma unroll
        for (int ti = 0; ti < 4; ++ti) Ff[ti] = *(const facc4*)&f_l[R0 + ti*16 + q*4];
        float G4[4];
        #pragma unroll
        for (int tj = 0; tj < 4; ++tj) G4[tj] = g_l[C0 + tj*16 + c0];
        float d = 0.f;
        #pragma unroll
        for (int ti = 0; ti < 4; ++ti)
            #pragma unroll
            for (int tj = 0; tj < 4; ++tj) {
                float gb = G4[tj] - 16.f;
                #pragma unroll
                for (int r = 0; r < 4; ++r) {
                    float cc = Cv[ti][tj][r];
                    d += EXP2F(Ff[ti][r] + gb - cc) * cc;
                }
            }
        d *= C2E;
        #pragma unroll
        for (int o = 1; o < 64; o <<= 1) d += __shfl_xor(d, o, 64);
        if ((t & 63) == 0) wredD[w] = d;
        __syncthreads();
        if (t == 0) {
            float s = 0.f;
            #pragma unroll
            for (int i = 0; i < 16; ++i) s += wredD[i];
            Dmat[a*B_SZ + b] = s;
            Dmat[b*B_SZ + a] = s;
        }
    }
}

// ---------------- K4: triplet scan + scalar outputs ----------------
__global__ void k_final(const float* __restrict__ dists, const float* __restrict__ Dmat,
                        const int* __restrict__ label, float* __restrict__ out) {
    __shared__ float ds[576], Dm[576];
    __shared__ int lab[B_SZ];
    __shared__ float wls[4]; __shared__ int wnp[4], wot[4];
    int t = threadIdx.x;
    for (int i = t; i < 576; i += 256) { ds[i] = dists[i]; Dm[i] = Dmat[i]; }
    if (t < B_SZ) lab[t] = label[t];
    __syncthreads();
    int np = 0, ot = 0; float wsum = 0.f;
    for (int idx = t; idx < 24*24*24; idx += 256) {
        int a2 = idx / 576;
        int rest = idx - a2*576;
        int p2 = rest / 24;
        int n2 = rest - p2*24;
        int la = lab[a2];
        if (la == lab[p2] && la != lab[n2]) {
            float diff = ds[a2*24 + n2] - ds[a2*24 + p2];
            if (diff > 0.f) {
                ++np;
                float dd = Dm[a2*24 + p2] - Dm[a2*24 + n2];
                if (dd > 0.f) { ++ot; wsum += dd; }
            }
        }
    }
    #pragma unroll
    for (int o = 1; o < 64; o <<= 1) {
        np += __shfl_xor(np, o, 64);
        ot += __shfl_xor(ot, o, 64);
        wsum += __shfl_xor(wsum, o, 64);
    }
    int w = t >> 6;
    if ((t & 63) == 0) { wnp[w] = np; wot[w] = ot; wls[w] = wsum; }
    __syncthreads();
    if (t == 0) {
        int tnp = wnp[0]+wnp[1]+wnp[2]+wnp[3];
        int tot = wot[0]+wot[1]+wot[2]+wot[3];
        float tws = wls[0]+wls[1]+wls[2]+wls[3];
        int den = tot > 1 ? tot : 1;
        float wl = (tws > 0.f) ? tws / (float)den : 0.f;
        out[240000] = wl;
        out[480001] = (float)tnp;
        out[480002] = (float)tot;
    }
}

extern "C" void kernel_launch(void* const* d_in, const int* in_sizes, int n_in,
                              void* d_out, int out_size, void* d_ws, size_t ws_size,
                              hipStream_t stream) {
    (void)in_sizes; (void)n_in; (void)out_size; (void)ws_size;
    const float* emb  = (const float*)d_in[0];
    const float* conv = (const float*)d_in[1];
    const float* kern = (const float*)d_in[2];
    const int*   lab  = (const int*)d_in[3];
    float* out = (float*)d_out;
    float* ws  = (float*)d_ws;
    float* embn  = ws;            // 12288 floats
    float* pnorm = ws + 12288;    // 6144
    float* dists = ws + 18432;    // 576
    float* Dmat  = ws + 19008;    // 576

    k_embnorm<<<1, 256, 0, stream>>>(emb, embn);
    k_pnorm<<<24, 256, 0, stream>>>(conv, pnorm);
    k_dists<<<144, 256, 0, stream>>>(embn, dists, Dmat);
    k_arcface<<<625, 256, 0, stream>>>(embn, kern, lab, out);
    k_pairs<<<276, 1024, 0, stream>>>(conv, pnorm, Dmat);
    k_final<<<1, 256, 0, stream>>>(dists, Dmat, lab, out);
}

// Round 3
// 204.126 us; speedup vs baseline: 1.9483x; 1.3871x over previous
//
#include <hip/hip_runtime.h>
#include <math.h>

#define B_SZ 24
#define D_EMBD 512
#define N_CLS 10000
#define CC 256
#define HH 196

#define S_SCALE 64.0f
#define COS_M 0.9004471023526769f
#define SIN_M 0.43496553411123023f
#define TH_C (-0.9004471023526769f)
#define MM_C 0.19573449035005357f
// base-2 scaled Sinkhorn units: Ceps2 = C * log2(e)/eps
#define KSC 14.4269504088896f          /* 10*log2(e) */
#define C2E 0.0693147180559945f        /* eps*ln2 */

typedef short bfrag8 __attribute__((ext_vector_type(8)));
typedef float facc4 __attribute__((ext_vector_type(4)));

#if __has_builtin(__builtin_amdgcn_exp2f)
#define EXP2F(x) __builtin_amdgcn_exp2f(x)
#else
#define EXP2F(x) exp2f(x)
#endif
#if __has_builtin(__builtin_amdgcn_logf)
#define LOG2F(x) __builtin_amdgcn_logf(x)
#else
#define LOG2F(x) __log2f(x)
#endif

__device__ inline unsigned short f2bf_rne(float x) {
    union { float f; unsigned u; } cv; cv.f = x;
    unsigned r = cv.u + 0x7FFFu + ((cv.u >> 16) & 1u);
    return (unsigned short)(r >> 16);
}
__device__ inline float bf2f(unsigned short h) {
    union { unsigned u; float f; } cv; cv.u = ((unsigned)h) << 16; return cv.f;
}

// ================= Launch 1: pairs (Sinkhorn) + emb gram =================
// blocks 0..275: one (a<b) pair each, 1024 thr (16 waves, 4x4 wave grid).
// blocks 276..311: 24x24 emb-cosine gram, one pair per wave. Block 276 zeros Dmat diag.
__global__ __launch_bounds__(1024) void k_pairs_all(const float* __restrict__ emb,
        const float* __restrict__ conv, float* __restrict__ dists,
        float* __restrict__ Dmat) {
    const int t = threadIdx.x;
    const int bid = blockIdx.x;

    if (bid >= 276) {
        // ---- emb gram path (no barriers used) ----
        int l = t & 63, w16 = t >> 6;
        if (bid == 276 && t < B_SZ) Dmat[t * B_SZ + t] = 0.f;
        int pid = (bid - 276) * 16 + w16;
        if (pid >= B_SZ * B_SZ) return;
        int i = pid / B_SZ, j = pid - (pid / B_SZ) * B_SZ;
        float sij = 0.f, sii = 0.f, sjj = 0.f;
        #pragma unroll
        for (int u = 0; u < 8; ++u) {
            float vi = emb[i*D_EMBD + u*64 + l];
            float vj = emb[j*D_EMBD + u*64 + l];
            sij = fmaf(vi, vj, sij); sii = fmaf(vi, vi, sii); sjj = fmaf(vj, vj, sjj);
        }
        #pragma unroll
        for (int o = 1; o < 64; o <<= 1) {
            sij += __shfl_xor(sij, o, 64);
            sii += __shfl_xor(sii, o, 64);
            sjj += __shfl_xor(sjj, o, 64);
        }
        if (l == 0) dists[pid] = sij * rsqrtf(sii * sjj);
        return;
    }

    __shared__ __align__(16) char smem[65536];
    // GEMM overlay: 4 staging buffers [256 rows][32 k] bf16 (16 KB each)
    unsigned short* Ah = (unsigned short*)smem;
    unsigned short* Al = Ah + 8192;
    unsigned short* Bh = Al + 8192;
    unsigned short* Bl = Bh + 8192;
    // Sinkhorn overlay (used strictly after GEMM's last fragment-read barrier)
    float* rowred = (float*)smem;        // [4][256]
    float* colred = rowred + 1024;       // [4][256]
    float* rm_l   = colred + 1024;       // [256]
    float* z_l    = rm_l + 256;          // [256]
    float* g_l    = z_l + 256;           // [256]
    float* na_s   = g_l + 256;           // [256]
    float* nb_s   = na_s + 256;          // [256]
    float* wredF  = nb_s + 256;          // [4]
    float* wredG  = wredF + 4;           // [4]
    float* wredD  = wredG + 4;           // [16]

    const int w = t >> 6;
    const int wr = w >> 2, wc = w & 3;
    const int q = (t >> 4) & 3, c0 = t & 15;
    const int R0 = wr * 64, C0 = wc * 64;

    // pair index -> (a, b), a < b
    int rem = bid, a = 0;
    while (rem >= 23 - a) { rem -= 23 - a; ++a; }
    int b = a + 1 + rem;
    const float* xa = conv + a*CC*HH;
    const float* xb = conv + b*CC*HH;

    const int sn = t >> 2;               // staging row 0..255
    const int sch = t & 3;               // staging 8-k chunk

    facc4 acc[4][4];
    #pragma unroll
    for (int i = 0; i < 4; ++i)
        #pragma unroll
        for (int j = 0; j < 4; ++j) acc[i][j] = (facc4){0.f, 0.f, 0.f, 0.f};

    float pa = 0.f, pb = 0.f;            // inline point-norm partials

    // ---- GEMM: G = Xa . Xb^T, K padded 196 -> 224, 7 K-steps of 32 ----
    for (int ks = 0; ks < 224; ks += 32) {
        __syncthreads();
        #pragma unroll
        for (int p = 0; p < 2; ++p) {
            int k0 = ks + sch*8;
            const float* src = (p ? xb : xa) + sn*HH + k0;
            float v[8];
            if (k0 + 8 <= HH) {
                const float4* s4 = (const float4*)src;
                float4 u0 = s4[0], u1 = s4[1];
                v[0]=u0.x; v[1]=u0.y; v[2]=u0.z; v[3]=u0.w;
                v[4]=u1.x; v[5]=u1.y; v[6]=u1.z; v[7]=u1.w;
            } else {
                #pragma unroll
                for (int j = 0; j < 8; ++j) v[j] = (k0 + j < HH) ? src[j] : 0.f;
            }
            float ps = 0.f;
            union { unsigned short s[8]; bfrag8 v8; } uh, ul;
            #pragma unroll
            for (int j = 0; j < 8; ++j) {
                ps = fmaf(v[j], v[j], ps);
                unsigned short hb = f2bf_rne(v[j]);
                uh.s[j] = hb;
                ul.s[j] = f2bf_rne(v[j] - bf2f(hb));
            }
            if (p) pb += ps; else pa += ps;
            unsigned short* dh = (p ? Bh : Ah) + sn*32 + sch*8;
            unsigned short* dl = (p ? Bl : Al) + sn*32 + sch*8;
            *(bfrag8*)dh = uh.v8;
            *(bfrag8*)dl = ul.v8;
        }
        __syncthreads();
        bfrag8 bh4[4], bl4[4];
        #pragma unroll
        for (int tj = 0; tj < 4; ++tj) {
            int col = C0 + tj*16 + c0;
            bh4[tj] = *(const bfrag8*)(Bh + col*32 + q*8);
            bl4[tj] = *(const bfrag8*)(Bl + col*32 + q*8);
        }
        #pragma unroll
        for (int ti = 0; ti < 4; ++ti) {
            int row = R0 + ti*16 + c0;
            bfrag8 ah = *(const bfrag8*)(Ah + row*32 + q*8);
            bfrag8 al = *(const bfrag8*)(Al + row*32 + q*8);
            #pragma unroll
            for (int tj = 0; tj < 4; ++tj) {
                acc[ti][tj] = __builtin_amdgcn_mfma_f32_16x16x32_bf16(ah, bh4[tj], acc[ti][tj], 0, 0, 0);
                acc[ti][tj] = __builtin_amdgcn_mfma_f32_16x16x32_bf16(ah, bl4[tj], acc[ti][tj], 0, 0, 0);
                acc[ti][tj] = __builtin_amdgcn_mfma_f32_16x16x32_bf16(al, bh4[tj], acc[ti][tj], 0, 0, 0);
            }
        }
    }
    __syncthreads();   // GEMM frag reads done; LDS reused for Sinkhorn

    // point norms: quad-reduce (4 threads per row, lane-adjacent)
    pa += __shfl_xor(pa, 1, 64); pa += __shfl_xor(pa, 2, 64);
    pb += __shfl_xor(pb, 1, 64); pb += __shfl_xor(pb, 2, 64);
    if (sch == 0) { na_s[sn] = pa; nb_s[sn] = pb; }
    if (t < 256) g_l[t] = 0.f;
    if (t < 4) wredG[t] = 0.f;
    __syncthreads();

    // C/D layout (16x16x32): row = R0 + ti*16 + q*4 + r, col = C0 + tj*16 + c0
    facc4 E[4][4];                        // first Ceps2, then 2^(rm - Ceps2)
    {
        float nbv[4];
        #pragma unroll
        for (int tj = 0; tj < 4; ++tj) nbv[tj] = nb_s[C0 + tj*16 + c0];
        #pragma unroll
        for (int ti = 0; ti < 4; ++ti) {
            facc4 nav = *(const facc4*)&na_s[R0 + ti*16 + q*4];
            #pragma unroll
            for (int tj = 0; tj < 4; ++tj) {
                #pragma unroll
                for (int r = 0; r < 4; ++r) {
                    float d2 = fmaxf(nav[r] + nbv[tj] - 2.f*acc[ti][tj][r], 0.f);
                    E[ti][tj][r] = KSC * sqrtf(d2 + 1e-12f);
                }
            }
        }
    }

    // tournament target indices (verified in R2)
    const int istar = ((c0&1)<<3) | ((c0&2)<<1) | ((c0&4)>>1) | ((c0&8)>>3);
    const int rowstar = R0 + (istar>>2)*16 + q*4 + (istar&3);
    const int tjstar = ((q&1)<<1) | (q>>1);
    const int colstar = C0 + tjstar*16 + c0;

    // ---- row mins of Ceps2 ----
    {
        float v16[16];
        #pragma unroll
        for (int ti = 0; ti < 4; ++ti)
            #pragma unroll
            for (int r = 0; r < 4; ++r)
                v16[ti*4+r] = fminf(fminf(E[ti][0][r], E[ti][1][r]),
                                    fminf(E[ti][2][r], E[ti][3][r]));
        #pragma unroll
        for (int p = 0; p < 4; ++p) {
            const int m = 1 << p, hsz = 8 >> p;
            const bool hi = (c0 >> p) & 1;
            #pragma unroll
            for (int j = 0; j < hsz; ++j) {
                float mine = hi ? v16[j+hsz] : v16[j];
                float send = hi ? v16[j] : v16[j+hsz];
                v16[j] = fminf(mine, __shfl_xor(send, m, 64));
            }
        }
        rowred[wc*256 + rowstar] = v16[0];
    }
    __syncthreads();
    if (t < 256)
        rm_l[t] = fminf(fminf(rowred[t], rowred[256+t]), fminf(rowred[512+t], rowred[768+t]));
    __syncthreads();

    // E := 2^(rm_r - Ceps2)
    #pragma unroll
    for (int ti = 0; ti < 4; ++ti) {
        facc4 rmv = *(const facc4*)&rm_l[R0 + ti*16 + q*4];
        #pragma unroll
        for (int tj = 0; tj < 4; ++tj)
            #pragma unroll
            for (int r = 0; r < 4; ++r)
                E[ti][tj][r] = EXP2F(rmv[r] - E[ti][tj][r]);
    }

    // ---- 6 Sinkhorn iterations (FMA inner loops) ----
    #pragma unroll 1
    for (int it = 0; it < 6; ++it) {
        // phase A: row sums  S_r = sum_c E * 2^(G_c - Gmax)
        float Gmax = fmaxf(fmaxf(wredG[0], wredG[1]), fmaxf(wredG[2], wredG[3]));
        float P4[4];
        #pragma unroll
        for (int tj = 0; tj < 4; ++tj) P4[tj] = EXP2F(g_l[C0 + tj*16 + c0] - Gmax);
        float v16[16];
        #pragma unroll
        for (int ti = 0; ti < 4; ++ti)
            #pragma unroll
            for (int r = 0; r < 4; ++r) {
                float s = 0.f;
                #pragma unroll
                for (int tj = 0; tj < 4; ++tj) s = fmaf(E[ti][tj][r], P4[tj], s);
                v16[ti*4+r] = s;
            }
        #pragma unroll
        for (int p = 0; p < 4; ++p) {
            const int m = 1 << p, hsz = 8 >> p;
            const bool hi = (c0 >> p) & 1;
            #pragma unroll
            for (int j = 0; j < hsz; ++j) {
                float mine = hi ? v16[j+hsz] : v16[j];
                float send = hi ? v16[j] : v16[j+hsz];
                v16[j] = mine + __shfl_xor(send, m, 64);
            }
        }
        rowred[wc*256 + rowstar] = v16[0];
        __syncthreads();
        // phase B: z_r = F_r - rm_r = 8 - Gmax - log2(S_r); wave-max -> wredF
        if (t < 256) {
            float s = rowred[t] + rowred[256+t] + rowred[512+t] + rowred[768+t];
            float z = 8.f - Gmax - LOG2F(s);
            z_l[t] = z;
            float m = z;
            #pragma unroll
            for (int o = 1; o < 64; o <<= 1) m = fmaxf(m, __shfl_xor(m, o, 64));
            if ((t & 63) == 0) wredF[t >> 6] = m;
        }
        __syncthreads();
        // phase C: col sums  S_c = sum_r E * 2^(z_r - M)
        float M = fmaxf(fmaxf(wredF[0], wredF[1]), fmaxf(wredF[2], wredF[3]));
        float Q[16];
        #pragma unroll
        for (int ti = 0; ti < 4; ++ti) {
            facc4 zv = *(const facc4*)&z_l[R0 + ti*16 + q*4];
            #pragma unroll
            for (int r = 0; r < 4; ++r) Q[ti*4+r] = EXP2F(zv[r] - M);
        }
        float w4[4];
        #pragma unroll
        for (int tj = 0; tj < 4; ++tj) {
            float s = 0.f;
            #pragma unroll
            for (int ti = 0; ti < 4; ++ti)
                #pragma unroll
                for (int r = 0; r < 4; ++r) s = fmaf(E[ti][tj][r], Q[ti*4+r], s);
            w4[tj] = s;
        }
        #pragma unroll
        for (int p = 0; p < 2; ++p) {
            const int m = 16 << p, hsz = 2 >> p;
            const bool hi = (q >> p) & 1;
            #pragma unroll
            for (int j = 0; j < hsz; ++j) {
                float mine = hi ? w4[j+hsz] : w4[j];
                float send = hi ? w4[j] : w4[j+hsz];
                w4[j] = mine + __shfl_xor(send, m, 64);
            }
        }
        colred[wr*256 + colstar] = w4[0];
        __syncthreads();
        // phase D: G_c = 8 - M - log2(S_c); wave-max -> wredG
        if (t < 256) {
            float s = colred[t] + colred[256+t] + colred[512+t] + colred[768+t];
            float G = 8.f - M - LOG2F(s);
            g_l[t] = G;
            float m = G;
            #pragma unroll
            for (int o = 1; o < 64; o <<= 1) m = fmaxf(m, __shfl_xor(m, o, 64));
            if ((t & 63) == 0) wredG[t >> 6] = m;
        }
        __syncthreads();
    }

    // ---- D = sum(T*C): T = 2^(z_r + G_c - 16 + log2 E), Ceps2 = rm_r - log2 E ----
    {
        float G4[4];
        #pragma unroll
        for (int tj = 0; tj < 4; ++tj) G4[tj] = g_l[C0 + tj*16 + c0] - 16.f;
        float d = 0.f;
        #pragma unroll
        for (int ti = 0; ti < 4; ++ti) {
            facc4 zv = *(const facc4*)&z_l[R0 + ti*16 + q*4];
            facc4 rmv = *(const facc4*)&rm_l[R0 + ti*16 + q*4];
            #pragma unroll
            for (int tj = 0; tj < 4; ++tj) {
                #pragma unroll
                for (int r = 0; r < 4; ++r) {
                    float e = fmaxf(E[ti][tj][r], 1e-45f);
                    float lE = LOG2F(e);
                    float ce = rmv[r] - lE;               // Ceps2
                    d = fmaf(EXP2F(zv[r] + G4[tj] + lE), ce, d);
                }
            }
        }
        d *= C2E;
        #pragma unroll
        for (int o = 1; o < 64; o <<= 1) d += __shfl_xor(d, o, 64);
        if ((t & 63) == 0) wredD[w] = d;
        __syncthreads();
        if (t == 0) {
            float s = 0.f;
            #pragma unroll
            for (int i = 0; i < 16; ++i) s += wredD[i];
            Dmat[a*B_SZ + b] = s;
            Dmat[b*B_SZ + a] = s;
        }
    }
}

// ================= Launch 2: arcface (blocks 0..312) + final (block 313) =================
__global__ __launch_bounds__(256) void k_arc_fin(const float* __restrict__ emb,
        const float* __restrict__ kern, const int* __restrict__ label,
        const float* __restrict__ dists, const float* __restrict__ Dmat,
        float* __restrict__ out) {
    const int t = threadIdx.x;
    const int bid = blockIdx.x;

    if (bid == 313) {
        // ---- triplet scan + scalar outputs ----
        __shared__ float ds[576], Dm[576];
        __shared__ int lab[B_SZ];
        __shared__ float wls[4]; __shared__ int wnp[4], wot[4];
        for (int i = t; i < 576; i += 256) { ds[i] = dists[i]; Dm[i] = Dmat[i]; }
        if (t < B_SZ) lab[t] = label[t];
        __syncthreads();
        int np = 0, ot = 0; float wsum = 0.f;
        for (int idx = t; idx < 24*24*24; idx += 256) {
            int a2 = idx / 576;
            int rest = idx - a2*576;
            int p2 = rest / 24;
            int n2 = rest - p2*24;
            int la = lab[a2];
            if (la == lab[p2] && la != lab[n2]) {
                float diff = ds[a2*24 + n2] - ds[a2*24 + p2];
                if (diff > 0.f) {
                    ++np;
                    float dd = Dm[a2*24 + p2] - Dm[a2*24 + n2];
                    if (dd > 0.f) { ++ot; wsum += dd; }
                }
            }
        }
        #pragma unroll
        for (int o = 1; o < 64; o <<= 1) {
            np += __shfl_xor(np, o, 64);
            ot += __shfl_xor(ot, o, 64);
            wsum += __shfl_xor(wsum, o, 64);
        }
        int w = t >> 6;
        if ((t & 63) == 0) { wnp[w] = np; wot[w] = ot; wls[w] = wsum; }
        __syncthreads();
        if (t == 0) {
            int tnp = wnp[0]+wnp[1]+wnp[2]+wnp[3];
            int tot = wot[0]+wot[1]+wot[2]+wot[3];
            float tws = wls[0]+wls[1]+wls[2]+wls[3];
            int den = tot > 1 ? tot : 1;
            float wl = (tws > 0.f) ? tws / (float)den : 0.f;
            out[240000] = wl;
            out[480001] = (float)tnp;
            out[480002] = (float)tot;
        }
        return;
    }

    // ---- arcface: 32 cols/block, self-normalizing ----
    __shared__ __align__(16) float es[B_SZ*D_EMBD];   // 48 KB raw emb; aliased later
    __shared__ float inv_s[B_SZ];
    __shared__ int lab_s[B_SZ];
    float* part = es;            // 8*800 floats, alias after acc done
    float* resb = es + 6400;     // 800 floats

    {
        const float4* s4 = (const float4*)emb;
        float4* d4 = (float4*)es;
        for (int i = t; i < (B_SZ*D_EMBD)/4; i += 256) d4[i] = s4[i];
    }
    if (t < B_SZ) lab_s[t] = label[t];
    __syncthreads();
    {   // row norms of emb (4 waves, 6 rows each)
        int l = t & 63, w = t >> 6;
        for (int r = w; r < B_SZ; r += 4) {
            float s = 0.f;
            #pragma unroll
            for (int u = 0; u < 8; ++u) { float v = es[r*D_EMBD + u*64 + l]; s = fmaf(v, v, s); }
            #pragma unroll
            for (int o = 1; o < 64; o <<= 1) s += __shfl_xor(s, o, 64);
            if (l == 0) inv_s[r] = rsqrtf(s);
        }
    }
    __syncthreads();

    const int cc = t & 31, kc = t >> 5;            // 32 cols, 8 k-chunks of 64
    int c = bid*32 + cc;
    int cL = c < N_CLS ? c : N_CLS - 1;
    float acc[B_SZ];
    #pragma unroll
    for (int r = 0; r < B_SZ; ++r) acc[r] = 0.f;
    float cn = 0.f;
    const int k0 = kc*64;
    for (int u = 0; u < 16; ++u) {
        int kb = k0 + u*4;
        float kv0 = kern[(kb+0)*N_CLS + cL];
        float kv1 = kern[(kb+1)*N_CLS + cL];
        float kv2 = kern[(kb+2)*N_CLS + cL];
        float kv3 = kern[(kb+3)*N_CLS + cL];
        cn = fmaf(kv0,kv0,cn); cn = fmaf(kv1,kv1,cn);
        cn = fmaf(kv2,kv2,cn); cn = fmaf(kv3,kv3,cn);
        #pragma unroll
        for (int r = 0; r < B_SZ; ++r) {
            const float4 e = *(const float4*)&es[r*D_EMBD + kb];
            acc[r] = fmaf(e.x, kv0, acc[r]);
            acc[r] = fmaf(e.y, kv1, acc[r]);
            acc[r] = fmaf(e.z, kv2, acc[r]);
            acc[r] = fmaf(e.w, kv3, acc[r]);
        }
    }
    __syncthreads();   // es reads done before aliased writes
    #pragma unroll
    for (int r = 0; r < B_SZ; ++r) part[kc*800 + cc*25 + r] = acc[r];
    part[kc*800 + cc*25 + 24] = cn;
    __syncthreads();
    for (int j = t; j < 800; j += 256) {
        float s = 0.f;
        #pragma unroll
        for (int kk = 0; kk < 8; ++kk) s += part[kk*800 + j];
        resb[j] = s;
    }
    __syncthreads();
    for (int o = t; o < 768; o += 256) {
        int r = o >> 5, c2 = o & 31;
        int col = bid*32 + c2;
        if (col >= N_CLS) continue;
        float dot = resb[c2*25 + r];
        float invk = rsqrtf(resb[c2*25 + 24]);
        float cosv = fminf(fmaxf(dot * inv_s[r] * invk, -1.f), 1.f);
        float oc = cosv * S_SCALE;
        float af = oc;
        if (lab_s[r] == col) {
            float tl = cosv;
            float sint = sqrtf(fmaxf(1.f - tl*tl, 0.f));
            float ctm = tl*COS_M - sint*SIN_M;
            float ftl = (tl > TH_C) ? ctm : (tl - MM_C);
            af = ftl * S_SCALE;
        }
        out[r*N_CLS + col] = af;
        out[240001 + r*N_CLS + col] = oc;
    }
}

extern "C" void kernel_launch(void* const* d_in, const int* in_sizes, int n_in,
                              void* d_out, int out_size, void* d_ws, size_t ws_size,
                              hipStream_t stream) {
    (void)in_sizes; (void)n_in; (void)out_size; (void)ws_size;
    const float* emb  = (const float*)d_in[0];
    const float* conv = (const float*)d_in[1];
    const float* kern = (const float*)d_in[2];
    const int*   lab  = (const int*)d_in[3];
    float* out = (float*)d_out;
    float* ws  = (float*)d_ws;
    float* dists = ws;            // 576 floats
    float* Dmat  = ws + 576;      // 576 floats

    k_pairs_all<<<312, 1024, 0, stream>>>(emb, conv, dists, Dmat);
    k_arc_fin<<<314, 256, 0, stream>>>(emb, kern, lab, dists, Dmat, out);
}